// Round 8
// baseline (206.775 us; speedup 1.0000x reference)
//
#include <hip/hip_runtime.h>

constexpr int K_CODES = 512;
constexpr int D_DIM   = 64;
constexpr int HW      = 4096;               // 64*64
constexpr int BATCH   = 32;
constexpr int N_ROWS  = BATCH * HW;         // 131072
constexpr int HALF    = BATCH * D_DIM * HW; // elements per output tensor
constexpr float MU    = 1e-4f;              // 5x over 1.9e-5 rigorous approx-vs-ref spread

typedef __attribute__((ext_vector_type(8))) short bf16x8;
typedef __attribute__((ext_vector_type(4))) float f32x4;

__device__ __forceinline__ unsigned short f32_bf16_rn(float x) {
    unsigned u = __builtin_bit_cast(unsigned, x);
    unsigned r = (u + 0x7FFFu + ((u >> 16) & 1u)) >> 16;   // round-to-nearest-even
    return (unsigned short)r;
}
__device__ __forceinline__ float bf16_f32(unsigned short h) {
    unsigned u = ((unsigned)h) << 16;
    return __builtin_bit_cast(float, u);
}

// prep: ee[k]=|e_k|^2 (bit-exact sequential f32, = reference) and interleaved
// two-term bf16 codebook: ehl[k*128 + d] = hi, ehl[k*128 + 64 + d] = lo
__global__ void prep(const float* __restrict__ emb, float* __restrict__ ee,
                     unsigned short* __restrict__ ehl) {
#pragma clang fp contract(off)
    int k = blockIdx.x * 256 + threadIdx.x;
    if (k >= K_CODES) return;
    const float* w = emb + k * D_DIM;
    float acc = 0.f;
    for (int d = 0; d < D_DIM; ++d) {
        float v = w[d];
        float q = v * v; acc = acc + q;
        unsigned short h = f32_bf16_rn(v);
        ehl[k * 128 + d]      = h;
        ehl[k * 128 + 64 + d] = f32_bf16_rn(v - bf16_f32(h));
    }
    ee[k] = acc;
}

// 256 thr = 4 waves; wave owns 16 rows x all 512 codes via 16x16x32 MFMA.
// Single pass tracks per-row top-2 approx dists (3 independent 2-MFMA chains).
// If gap > MU: approx argmin provably == reference argmin (done, 99.4% rows).
// Else: wave-cooperative bit-exact 512-code re-scan (validated recipe, rounds 2-7).
__global__ __launch_bounds__(256, 8) void vq_top2(const float* __restrict__ zin,
                                                  const float* __restrict__ emb,
                                                  const float* __restrict__ ee,
                                                  const unsigned short* __restrict__ ehl,
                                                  float* __restrict__ out) {
#pragma clang fp contract(off)
    __shared__ float s_ee[K_CODES];
    __shared__ int   s_win[64];

    const int tid  = threadIdx.x;
    const int wid  = tid >> 6;
    const int lane = tid & 63;
    const int l15  = lane & 15;
    const int lq   = lane >> 4;          // 0..3 = k-quarter

    s_ee[tid]       = ee[tid];
    s_ee[tid + 256] = ee[tid + 256];
    __syncthreads();

    const int rowbase = blockIdx.x * 64 + wid * 16;
    const int n0 = rowbase + l15;
    const float* zp = zin + (size_t)(n0 >> 12) * (D_DIM * HW) + (n0 & (HW - 1));

    // z B-fragments (layout validated round 7): col=l15, k = s*32 + lq*8 + j
    bf16x8 zh[2], zl[2];
#pragma unroll
    for (int s = 0; s < 2; ++s) {
        float rz[8];
#pragma unroll
        for (int j = 0; j < 8; ++j)
            rz[j] = zp[(size_t)(s * 32 + lq * 8 + j) * HW];
#pragma unroll
        for (int j = 0; j < 8; ++j) {
            unsigned short h = f32_bf16_rn(rz[j]);
            zh[s][j] = (short)h;
            zl[s][j] = (short)f32_bf16_rn(rz[j] - bf16_f32(h));
        }
    }

    float m1 = 3.4e38f, m2 = 3.4e38f;
    int   i1 = 0;

    for (int ct = 0; ct < 32; ++ct) {
        const int crow = ct * 16 + l15;                    // A row = code
        const short* ap = (const short*)(ehl + (size_t)crow * 128);
        const bf16x8 ah0 = *(const bf16x8*)(ap + lq * 8);
        const bf16x8 ah1 = *(const bf16x8*)(ap + 32 + lq * 8);
        const bf16x8 al0 = *(const bf16x8*)(ap + 64 + lq * 8);
        const bf16x8 al1 = *(const bf16x8*)(ap + 96 + lq * 8);
        f32x4 a0 = {0.f,0.f,0.f,0.f}, a1 = {0.f,0.f,0.f,0.f}, a2 = {0.f,0.f,0.f,0.f};
        a0 = __builtin_amdgcn_mfma_f32_16x16x32_bf16(ah0, zh[0], a0, 0, 0, 0);
        a1 = __builtin_amdgcn_mfma_f32_16x16x32_bf16(al0, zh[0], a1, 0, 0, 0);
        a2 = __builtin_amdgcn_mfma_f32_16x16x32_bf16(ah0, zl[0], a2, 0, 0, 0);
        a0 = __builtin_amdgcn_mfma_f32_16x16x32_bf16(ah1, zh[1], a0, 0, 0, 0);
        a1 = __builtin_amdgcn_mfma_f32_16x16x32_bf16(al1, zh[1], a1, 0, 0, 0);
        a2 = __builtin_amdgcn_mfma_f32_16x16x32_bf16(ah1, zl[1], a2, 0, 0, 0);
        const f32x4 ev = *(const f32x4*)&s_ee[ct * 16 + lq * 4];
#pragma unroll
        for (int r = 0; r < 4; ++r) {
            const float ssum = (a0[r] + a1[r]) + a2[r];
            const float dist = __builtin_fmaf(-2.f, ssum, ev[r]);
            const float hi   = fmaxf(m1, dist);
            m2 = fminf(m2, hi);
            const bool lt = dist < m1;
            i1 = lt ? (ct * 16 + lq * 4 + r) : i1;
            m1 = fminf(m1, dist);
        }
    }

    // merge top-2 across the 4 k-quarters (lanes xor 16, 32)
#pragma unroll
    for (int mk = 16; mk <= 32; mk <<= 1) {
        const float om1 = __shfl_xor(m1, mk, 64);
        const float om2 = __shfl_xor(m2, mk, 64);
        const int   oi  = __shfl_xor(i1, mk, 64);
        const float hi  = fmaxf(m1, om1);
        m2 = fminf(fminf(m2, om2), hi);
        const bool take = om1 < m1;
        i1 = take ? oi : i1;
        m1 = fminf(m1, om1);
    }

    const bool flagged = (m2 <= m1 + MU);
    if (lane < 16 && !flagged) s_win[wid * 16 + l15] = i1;

    unsigned long long fmask = __ballot(flagged) & 0xFFFFull;

    // slow path: bit-exact full scan for ambiguous rows (~0.6%), wave-cooperative
    while (fmask) {
        const int R = __builtin_ctzll(fmask);
        fmask &= fmask - 1;
        const int n = rowbase + R;
        const float* zq = zin + (size_t)(n >> 12) * (D_DIM * HW) + (n & (HW - 1));

        float zz = 0.f;                         // sequential, separate rounding
        for (int d = 0; d < D_DIM; ++d) {
            const float v = zq[(size_t)d * HW]; // broadcast load (same addr all lanes)
            const float q = v * v; zz = zz + q;
        }
        const int k0 = lane * 8;
        float dot[8];
#pragma unroll
        for (int j = 0; j < 8; ++j) dot[j] = 0.f;
        for (int d = 0; d < D_DIM; ++d) {
            const float zd = zq[(size_t)d * HW];
#pragma unroll
            for (int j = 0; j < 8; ++j)
                dot[j] = __builtin_fmaf(emb[(size_t)(k0 + j) * D_DIM + d], zd, dot[j]);
        }
        float bd = 3.4e38f; int bidx = 0;
#pragma unroll
        for (int j = 0; j < 8; ++j) {
            const float mm = 2.0f * dot[j];
            const float s  = zz - mm;
            const float dist = s + s_ee[k0 + j];
            if (dist < bd) { bd = dist; bidx = k0 + j; }
        }
#pragma unroll
        for (int mk = 1; mk <= 32; mk <<= 1) {  // lexicographic (dist, idx) min
            const float od = __shfl_xor(bd, mk, 64);
            const int   oi = __shfl_xor(bidx, mk, 64);
            const bool take = (od < bd) || (od == bd && oi < bidx);
            bd   = take ? od : bd;
            bidx = take ? oi : bidx;
        }
        if (lane == 0) s_win[wid * 16 + R] = bidx;
    }
    __syncthreads();

    // epilogue: gather + coalesced write of both outputs (64 rows x 64 d)
    const int drow = tid & 63;
    const int dgrp = tid >> 6;                  // d-quarter
    const int n2   = blockIdx.x * 64 + drow;
    float* o1 = out + (size_t)(n2 >> 12) * (D_DIM * HW) + (n2 & (HW - 1));
    float* o2 = o1 + HALF;
    const float* wv = emb + (size_t)s_win[drow] * D_DIM;
#pragma unroll
    for (int dd = 0; dd < 16; ++dd) {
        const int d = dgrp * 16 + dd;
        const float v = wv[d];
        o1[(size_t)d * HW] = v;
        o2[(size_t)d * HW] = v;
    }
}

// fallback (validated round-2 kernel) if ws too small
__global__ __launch_bounds__(256) void vq_fallback(const float* __restrict__ zin,
                                                   const float* __restrict__ emb,
                                                   float* __restrict__ out) {
#pragma clang fp contract(off)
    __shared__ float s_ee[K_CODES];
    const int tid = threadIdx.x;
    for (int k = tid; k < K_CODES; k += 256) {
        const float* w = emb + k * D_DIM;
        float acc = 0.f;
        for (int d = 0; d < D_DIM; ++d) { float q = w[d] * w[d]; acc = acc + q; }
        s_ee[k] = acc;
    }
    __syncthreads();
    const int n = blockIdx.x * 256 + tid;
    const int b = n >> 12;
    const int p = n & (HW - 1);
    const float* zp = zin + (size_t)b * (D_DIM * HW) + p;
    float zr[D_DIM];
#pragma unroll
    for (int d = 0; d < D_DIM; ++d) zr[d] = zp[(size_t)d * HW];
    float zz = 0.f;
#pragma unroll
    for (int d = 0; d < D_DIM; ++d) { float q = zr[d] * zr[d]; zz = zz + q; }
    float best = 3.4e38f; int bi = 0;
    for (int k0 = 0; k0 < K_CODES; k0 += 8) {
        const float* w = emb + (size_t)k0 * D_DIM;
        float dot[8];
#pragma unroll
        for (int j = 0; j < 8; ++j) dot[j] = 0.f;
#pragma unroll
        for (int d = 0; d < D_DIM; ++d) {
            const float z = zr[d];
#pragma unroll
            for (int j = 0; j < 8; ++j)
                dot[j] = __builtin_fmaf(w[j * D_DIM + d], z, dot[j]);
        }
#pragma unroll
        for (int j = 0; j < 8; ++j) {
            const float m = 2.0f * dot[j];
            const float s = zz - m;
            const float dist = s + s_ee[k0 + j];
            if (dist < best) { best = dist; bi = k0 + j; }
        }
    }
    const float* wb = emb + (size_t)bi * D_DIM;
    float* o1 = out + (size_t)b * (D_DIM * HW) + p;
    float* o2 = o1 + HALF;
#pragma unroll
    for (int d = 0; d < D_DIM; ++d) {
        const float v = wb[d];
        o1[(size_t)d * HW] = v;
        o2[(size_t)d * HW] = v;
    }
}

extern "C" void kernel_launch(void* const* d_in, const int* in_sizes, int n_in,
                              void* d_out, int out_size, void* d_ws, size_t ws_size,
                              hipStream_t stream) {
    const float* z   = (const float*)d_in[0];
    const float* emb = (const float*)d_in[1];
    float* out = (float*)d_out;

    const size_t need = 2048 + (size_t)K_CODES * 128 * sizeof(unsigned short);
    if (ws_size >= need) {
        float* ee = (float*)d_ws;
        unsigned short* ehl = (unsigned short*)((char*)d_ws + 2048);
        hipLaunchKernelGGL(prep, dim3(2), dim3(256), 0, stream, emb, ee, ehl);
        hipLaunchKernelGGL(vq_top2, dim3(N_ROWS / 64), dim3(256), 0, stream,
                           z, emb, ee, ehl, out);
    } else {
        hipLaunchKernelGGL(vq_fallback, dim3(N_ROWS / 256), dim3(256), 0, stream,
                           z, emb, out);
    }
}

// Round 10
// 202.212 us; speedup vs baseline: 1.0226x; 1.0226x over previous
//
#include <hip/hip_runtime.h>

constexpr int K_CODES = 512;
constexpr int D_DIM   = 64;
constexpr int HW      = 4096;               // 64*64
constexpr int BATCH   = 32;
constexpr int N_ROWS  = BATCH * HW;         // 131072
constexpr int HALF    = BATCH * D_DIM * HW; // elements per output tensor
constexpr float MU    = 1e-4f;              // 5x over ~1.9e-5 approx-vs-ref spread

typedef __attribute__((ext_vector_type(8))) short bf16x8;
typedef __attribute__((ext_vector_type(4))) float f32x4;

__device__ __forceinline__ unsigned short f32_bf16_rn(float x) {
    unsigned u = __builtin_bit_cast(unsigned, x);
    unsigned r = (u + 0x7FFFu + ((u >> 16) & 1u)) >> 16;   // round-to-nearest-even
    return (unsigned short)r;
}
__device__ __forceinline__ float bf16_f32(unsigned short h) {
    unsigned u = ((unsigned)h) << 16;
    return __builtin_bit_cast(float, u);
}

// prep: ee[k]=|e_k|^2 (bit-exact sequential f32, = reference) and interleaved
// two-term bf16 codebook: ehl[k*128 + d] = hi, ehl[k*128 + 64 + d] = lo
__global__ void prep(const float* __restrict__ emb, float* __restrict__ ee,
                     unsigned short* __restrict__ ehl) {
#pragma clang fp contract(off)
    int k = blockIdx.x * 256 + threadIdx.x;
    if (k >= K_CODES) return;
    const float* w = emb + k * D_DIM;
    float acc = 0.f;
    for (int d = 0; d < D_DIM; ++d) {
        float v = w[d];
        float q = v * v; acc = acc + q;
        unsigned short h = f32_bf16_rn(v);
        ehl[k * 128 + d]      = h;
        ehl[k * 128 + 64 + d] = f32_bf16_rn(v - bf16_f32(h));
    }
    ee[k] = acc;
}

// ROUND-8 KERNEL VERBATIM (passed both validations) with ONE change:
// __launch_bounds__(256, 8) -> (256, 4). Round 8's VGPR_Count=32 proved the
// 64-reg cap forced spill/remat of the ~90-reg live set (MfmaUtil 4.9%).
// Cap 128 fits it spill-free; ILP (3 indep MFMA chains) hides latency.
// 256 thr = 4 waves; wave owns 16 rows x all 512 codes via 16x16x32 MFMA.
// Single pass tracks per-row top-2 approx dists.
// gap > MU: approx argmin provably == reference argmin (99.4% rows).
// Else: wave-cooperative bit-exact 512-code re-scan (validated recipe).
__global__ __launch_bounds__(256, 4) void vq_top2(const float* __restrict__ zin,
                                                  const float* __restrict__ emb,
                                                  const float* __restrict__ ee,
                                                  const unsigned short* __restrict__ ehl,
                                                  float* __restrict__ out) {
#pragma clang fp contract(off)
    __shared__ float s_ee[K_CODES];
    __shared__ int   s_win[64];

    const int tid  = threadIdx.x;
    const int wid  = tid >> 6;
    const int lane = tid & 63;
    const int l15  = lane & 15;
    const int lq   = lane >> 4;          // 0..3 = k-quarter

    s_ee[tid]       = ee[tid];
    s_ee[tid + 256] = ee[tid + 256];
    __syncthreads();

    const int rowbase = blockIdx.x * 64 + wid * 16;
    const int n0 = rowbase + l15;
    const float* zp = zin + (size_t)(n0 >> 12) * (D_DIM * HW) + (n0 & (HW - 1));

    // z B-fragments (layout validated rounds 7-8): col=l15, k = s*32 + lq*8 + j
    bf16x8 zh[2], zl[2];
#pragma unroll
    for (int s = 0; s < 2; ++s) {
        float rz[8];
#pragma unroll
        for (int j = 0; j < 8; ++j)
            rz[j] = zp[(size_t)(s * 32 + lq * 8 + j) * HW];
#pragma unroll
        for (int j = 0; j < 8; ++j) {
            unsigned short h = f32_bf16_rn(rz[j]);
            zh[s][j] = (short)h;
            zl[s][j] = (short)f32_bf16_rn(rz[j] - bf16_f32(h));
        }
    }

    float m1 = 3.4e38f, m2 = 3.4e38f;
    int   i1 = 0;

#pragma unroll 2
    for (int ct = 0; ct < 32; ++ct) {
        const int crow = ct * 16 + l15;                    // A row = code
        const short* ap = (const short*)(ehl + (size_t)crow * 128);
        const bf16x8 ah0 = *(const bf16x8*)(ap + lq * 8);
        const bf16x8 ah1 = *(const bf16x8*)(ap + 32 + lq * 8);
        const bf16x8 al0 = *(const bf16x8*)(ap + 64 + lq * 8);
        const bf16x8 al1 = *(const bf16x8*)(ap + 96 + lq * 8);
        f32x4 a0 = {0.f,0.f,0.f,0.f}, a1 = {0.f,0.f,0.f,0.f}, a2 = {0.f,0.f,0.f,0.f};
        a0 = __builtin_amdgcn_mfma_f32_16x16x32_bf16(ah0, zh[0], a0, 0, 0, 0);
        a1 = __builtin_amdgcn_mfma_f32_16x16x32_bf16(al0, zh[0], a1, 0, 0, 0);
        a2 = __builtin_amdgcn_mfma_f32_16x16x32_bf16(ah0, zl[0], a2, 0, 0, 0);
        a0 = __builtin_amdgcn_mfma_f32_16x16x32_bf16(ah1, zh[1], a0, 0, 0, 0);
        a1 = __builtin_amdgcn_mfma_f32_16x16x32_bf16(al1, zh[1], a1, 0, 0, 0);
        a2 = __builtin_amdgcn_mfma_f32_16x16x32_bf16(ah1, zl[1], a2, 0, 0, 0);
        const f32x4 ev = *(const f32x4*)&s_ee[ct * 16 + lq * 4];
#pragma unroll
        for (int r = 0; r < 4; ++r) {
            const float ssum = (a0[r] + a1[r]) + a2[r];
            const float dist = __builtin_fmaf(-2.f, ssum, ev[r]);
            const float hi   = fmaxf(m1, dist);
            m2 = fminf(m2, hi);
            const bool lt = dist < m1;
            i1 = lt ? (ct * 16 + lq * 4 + r) : i1;
            m1 = fminf(m1, dist);
        }
    }

    // merge top-2 across the 4 k-quarters (lanes xor 16, 32)
#pragma unroll
    for (int mk = 16; mk <= 32; mk <<= 1) {
        const float om1 = __shfl_xor(m1, mk, 64);
        const float om2 = __shfl_xor(m2, mk, 64);
        const int   oi  = __shfl_xor(i1, mk, 64);
        const float hi  = fmaxf(m1, om1);
        m2 = fminf(fminf(m2, om2), hi);
        const bool take = om1 < m1;
        i1 = take ? oi : i1;
        m1 = fminf(m1, om1);
    }

    const bool flagged = (m2 <= m1 + MU);
    if (lane < 16 && !flagged) s_win[wid * 16 + l15] = i1;

    unsigned long long fmask = __ballot(flagged) & 0xFFFFull;

    // slow path: bit-exact full scan for ambiguous rows (~0.6%), wave-cooperative
    while (fmask) {
        const int R = __builtin_ctzll(fmask);
        fmask &= fmask - 1;
        const int n = rowbase + R;
        const float* zq = zin + (size_t)(n >> 12) * (D_DIM * HW) + (n & (HW - 1));

        float zz = 0.f;                         // sequential, separate rounding
        for (int d = 0; d < D_DIM; ++d) {
            const float v = zq[(size_t)d * HW]; // broadcast load (same addr all lanes)
            const float q = v * v; zz = zz + q;
        }
        const int k0 = lane * 8;
        float dot[8];
#pragma unroll
        for (int j = 0; j < 8; ++j) dot[j] = 0.f;
        for (int d = 0; d < D_DIM; ++d) {
            const float zd = zq[(size_t)d * HW];
#pragma unroll
            for (int j = 0; j < 8; ++j)
                dot[j] = __builtin_fmaf(emb[(size_t)(k0 + j) * D_DIM + d], zd, dot[j]);
        }
        float bd = 3.4e38f; int bidx = 0;
#pragma unroll
        for (int j = 0; j < 8; ++j) {
            const float mm = 2.0f * dot[j];
            const float s  = zz - mm;
            const float dist = s + s_ee[k0 + j];
            if (dist < bd) { bd = dist; bidx = k0 + j; }
        }
#pragma unroll
        for (int mk = 1; mk <= 32; mk <<= 1) {  // lexicographic (dist, idx) min
            const float od = __shfl_xor(bd, mk, 64);
            const int   oi = __shfl_xor(bidx, mk, 64);
            const bool take = (od < bd) || (od == bd && oi < bidx);
            bd   = take ? od : bd;
            bidx = take ? oi : bidx;
        }
        if (lane == 0) s_win[wid * 16 + R] = bidx;
    }
    __syncthreads();

    // epilogue: gather + coalesced write of both outputs (64 rows x 64 d)
    const int drow = tid & 63;
    const int dgrp = tid >> 6;                  // d-quarter
    const int n2   = blockIdx.x * 64 + drow;
    float* o1 = out + (size_t)(n2 >> 12) * (D_DIM * HW) + (n2 & (HW - 1));
    float* o2 = o1 + HALF;
    const float* wv = emb + (size_t)s_win[drow] * D_DIM;
#pragma unroll
    for (int dd = 0; dd < 16; ++dd) {
        const int d = dgrp * 16 + dd;
        const float v = wv[d];
        o1[(size_t)d * HW] = v;
        o2[(size_t)d * HW] = v;
    }
}

// fallback (validated round-2 kernel) if ws too small
__global__ __launch_bounds__(256) void vq_fallback(const float* __restrict__ zin,
                                                   const float* __restrict__ emb,
                                                   float* __restrict__ out) {
#pragma clang fp contract(off)
    __shared__ float s_ee[K_CODES];
    const int tid = threadIdx.x;
    for (int k = tid; k < K_CODES; k += 256) {
        const float* w = emb + k * D_DIM;
        float acc = 0.f;
        for (int d = 0; d < D_DIM; ++d) { float q = w[d] * w[d]; acc = acc + q; }
        s_ee[k] = acc;
    }
    __syncthreads();
    const int n = blockIdx.x * 256 + tid;
    const int b = n >> 12;
    const int p = n & (HW - 1);
    const float* zp = zin + (size_t)b * (D_DIM * HW) + p;
    float zr[D_DIM];
#pragma unroll
    for (int d = 0; d < D_DIM; ++d) zr[d] = zp[(size_t)d * HW];
    float zz = 0.f;
#pragma unroll
    for (int d = 0; d < D_DIM; ++d) { float q = zr[d] * zr[d]; zz = zz + q; }
    float best = 3.4e38f; int bi = 0;
    for (int k0 = 0; k0 < K_CODES; k0 += 8) {
        const float* w = emb + (size_t)k0 * D_DIM;
        float dot[8];
#pragma unroll
        for (int j = 0; j < 8; ++j) dot[j] = 0.f;
#pragma unroll
        for (int d = 0; d < D_DIM; ++d) {
            const float z = zr[d];
#pragma unroll
            for (int j = 0; j < 8; ++j)
                dot[j] = __builtin_fmaf(w[j * D_DIM + d], z, dot[j]);
        }
#pragma unroll
        for (int j = 0; j < 8; ++j) {
            const float m = 2.0f * dot[j];
            const float s = zz - m;
            const float dist = s + s_ee[k0 + j];
            if (dist < best) { best = dist; bi = k0 + j; }
        }
    }
    const float* wb = emb + (size_t)bi * D_DIM;
    float* o1 = out + (size_t)b * (D_DIM * HW) + p;
    float* o2 = o1 + HALF;
#pragma unroll
    for (int d = 0; d < D_DIM; ++d) {
        const float v = wb[d];
        o1[(size_t)d * HW] = v;
        o2[(size_t)d * HW] = v;
    }
}

extern "C" void kernel_launch(void* const* d_in, const int* in_sizes, int n_in,
                              void* d_out, int out_size, void* d_ws, size_t ws_size,
                              hipStream_t stream) {
    const float* z   = (const float*)d_in[0];
    const float* emb = (const float*)d_in[1];
    float* out = (float*)d_out;

    const size_t need = 2048 + (size_t)K_CODES * 128 * sizeof(unsigned short);
    if (ws_size >= need) {
        float* ee = (float*)d_ws;
        unsigned short* ehl = (unsigned short*)((char*)d_ws + 2048);
        hipLaunchKernelGGL(prep, dim3(2), dim3(256), 0, stream, emb, ee, ehl);
        hipLaunchKernelGGL(vq_top2, dim3(N_ROWS / 64), dim3(256), 0, stream,
                           z, emb, ee, ehl, out);
    } else {
        hipLaunchKernelGGL(vq_fallback, dim3(N_ROWS / 256), dim3(256), 0, stream,
                           z, emb, out);
    }
}

// Round 11
// 167.745 us; speedup vs baseline: 1.2327x; 1.2055x over previous
//
#include <hip/hip_runtime.h>

constexpr int K_CODES = 512;
constexpr int D_DIM   = 64;
constexpr int HW      = 4096;               // 64*64
constexpr int BATCH   = 32;
constexpr int N_ROWS  = BATCH * HW;         // 131072
constexpr int HALF    = BATCH * D_DIM * HW; // elements per output tensor
constexpr float MU    = 1e-4f;              // 5x over ~1.9e-5 approx-vs-ref spread

constexpr int TILE_C  = 64;                 // codes per LDS tile (16 KB split form)
constexpr int N_TILES = K_CODES / TILE_C;   // 8
constexpr int CT_TILE = TILE_C / 16;        // 4 MFMA code-groups per tile
constexpr int RPB     = 128;                // rows per block (4 waves x 32)

typedef __attribute__((ext_vector_type(8))) short bf16x8;
typedef __attribute__((ext_vector_type(4))) float f32x4;

__device__ __forceinline__ unsigned short f32_bf16_rn(float x) {
    unsigned u = __builtin_bit_cast(unsigned, x);
    unsigned r = (u + 0x7FFFu + ((u >> 16) & 1u)) >> 16;   // round-to-nearest-even
    return (unsigned short)r;
}
__device__ __forceinline__ float bf16_f32(unsigned short h) {
    unsigned u = ((unsigned)h) << 16;
    return __builtin_bit_cast(float, u);
}

// prep: ee[k]=|e_k|^2 (bit-exact sequential f32, = reference) and interleaved
// two-term bf16 codebook: ehl[k*128 + d] = hi, ehl[k*128 + 64 + d] = lo
__global__ void prep(const float* __restrict__ emb, float* __restrict__ ee,
                     unsigned short* __restrict__ ehl) {
#pragma clang fp contract(off)
    int k = blockIdx.x * 256 + threadIdx.x;
    if (k >= K_CODES) return;
    const float* w = emb + k * D_DIM;
    float acc = 0.f;
    for (int d = 0; d < D_DIM; ++d) {
        float v = w[d];
        float q = v * v; acc = acc + q;
        unsigned short h = f32_bf16_rn(v);
        ehl[k * 128 + d]      = h;
        ehl[k * 128 + 64 + d] = f32_bf16_rn(v - bf16_f32(h));
    }
    ee[k] = acc;
}

// 256 thr = 4 waves; wave owns 32 rows (2 rowgroups). Codebook streamed through
// LDS in 64-code double-buffered tiles (T14 split staging), XOR-swizzled so
// ds_read_b128 fragments are conflict-free. Single-pass per-row top-2 via
// 16x16x32 bf16 MFMA with two-term z/e split (validated rounds 7-10).
// gap > MU: approx argmin provably == reference argmin. Else: wave-cooperative
// bit-exact 512-code scan (validated recipe, absmax 0.0).
__global__ __launch_bounds__(256, 4) void vq_top2(const float* __restrict__ zin,
                                                  const float* __restrict__ emb,
                                                  const float* __restrict__ ee,
                                                  const unsigned short* __restrict__ ehl,
                                                  float* __restrict__ out) {
#pragma clang fp contract(off)
    __shared__ __attribute__((aligned(16))) short s_cb[2][TILE_C * 128]; // 2 x 16 KB
    __shared__ __attribute__((aligned(16))) float s_ee[K_CODES];
    __shared__ int s_win[RPB];

    const int tid  = threadIdx.x;
    const int wid  = tid >> 6;
    const int lane = tid & 63;
    const int l15  = lane & 15;
    const int lq   = lane >> 4;          // 0..3 = k-quarter

    s_ee[tid]       = ee[tid];
    s_ee[tid + 256] = ee[tid + 256];

    const int rowbase = blockIdx.x * RPB + wid * 32;

    // z B-fragments for 2 rowgroups (layout validated rounds 7-10):
    // col = l15, k = s*32 + lq*8 + j
    bf16x8 zh[2][2], zl[2][2];
#pragma unroll
    for (int rg = 0; rg < 2; ++rg) {
        const int n0 = rowbase + rg * 16 + l15;
        const float* zp = zin + (size_t)(n0 >> 12) * (D_DIM * HW) + (n0 & (HW - 1));
#pragma unroll
        for (int s = 0; s < 2; ++s) {
            float rz[8];
#pragma unroll
            for (int j = 0; j < 8; ++j)
                rz[j] = zp[(size_t)(s * 32 + lq * 8 + j) * HW];
#pragma unroll
            for (int j = 0; j < 8; ++j) {
                unsigned short h = f32_bf16_rn(rz[j]);
                zh[rg][s][j] = (short)h;
                zl[rg][s][j] = (short)f32_bf16_rn(rz[j] - bf16_f32(h));
            }
        }
    }

    // per-lane swizzled fragment byte offsets within a ct-block.
    // logical: row = ct*16+l15 (256 B/row), col16 = h*8 + s*4 + lq
    // swizzle: col16 ^= row&7  (= l15&7; ct*16 is 0 mod 8) -> conflict-free reads
    int fb[4];
#pragma unroll
    for (int h = 0; h < 2; ++h)
#pragma unroll
        for (int s = 0; s < 2; ++s)
            fb[h * 2 + s] = l15 * 256 + (((h * 8 + s * 4 + lq) ^ (l15 & 7)) << 4);

    // prologue: stage tile 0 into buffer 0 (linear global read, swizzled LDS write)
    {
        f32x4 stg[4];
#pragma unroll
        for (int r = 0; r < 4; ++r)
            stg[r] = *(const f32x4*)((const char*)ehl + r * 4096 + tid * 16);
#pragma unroll
        for (int r = 0; r < 4; ++r) {
            const int o   = r * 4096 + tid * 16;
            const int row = o >> 8;
            const int c16 = (o >> 4) & 15;
            const int so  = (o & ~255) | ((c16 ^ (row & 7)) << 4);
            *(f32x4*)((char*)s_cb[0] + so) = stg[r];
        }
    }
    __syncthreads();

    float m1[2] = {3.4e38f, 3.4e38f}, m2[2] = {3.4e38f, 3.4e38f};
    int   i1[2] = {0, 0};

    int cur = 0;
    for (int t = 0; t < N_TILES; ++t) {
        // T14 split: issue next tile's global loads BEFORE compute...
        f32x4 stg[4];
        const bool pre = (t + 1 < N_TILES);
        if (pre) {
            const char* src = (const char*)ehl + (size_t)(t + 1) * (TILE_C * 256);
#pragma unroll
            for (int r = 0; r < 4; ++r)
                stg[r] = *(const f32x4*)(src + r * 4096 + tid * 16);
        }

        const char* cb = (const char*)s_cb[cur];
#pragma unroll
        for (int ct = 0; ct < CT_TILE; ++ct) {
            const bf16x8 ah0 = *(const bf16x8*)(cb + ct * 4096 + fb[0]);
            const bf16x8 ah1 = *(const bf16x8*)(cb + ct * 4096 + fb[1]);
            const bf16x8 al0 = *(const bf16x8*)(cb + ct * 4096 + fb[2]);
            const bf16x8 al1 = *(const bf16x8*)(cb + ct * 4096 + fb[3]);
            const int gct = t * CT_TILE + ct;
            const f32x4 ev = *(const f32x4*)&s_ee[gct * 16 + lq * 4];
#pragma unroll
            for (int rg = 0; rg < 2; ++rg) {
                f32x4 a0 = {0.f,0.f,0.f,0.f}, a1 = {0.f,0.f,0.f,0.f}, a2 = {0.f,0.f,0.f,0.f};
                a0 = __builtin_amdgcn_mfma_f32_16x16x32_bf16(ah0, zh[rg][0], a0, 0, 0, 0);
                a1 = __builtin_amdgcn_mfma_f32_16x16x32_bf16(al0, zh[rg][0], a1, 0, 0, 0);
                a2 = __builtin_amdgcn_mfma_f32_16x16x32_bf16(ah0, zl[rg][0], a2, 0, 0, 0);
                a0 = __builtin_amdgcn_mfma_f32_16x16x32_bf16(ah1, zh[rg][1], a0, 0, 0, 0);
                a1 = __builtin_amdgcn_mfma_f32_16x16x32_bf16(al1, zh[rg][1], a1, 0, 0, 0);
                a2 = __builtin_amdgcn_mfma_f32_16x16x32_bf16(ah1, zl[rg][1], a2, 0, 0, 0);
#pragma unroll
                for (int r = 0; r < 4; ++r) {
                    const float ssum = (a0[r] + a1[r]) + a2[r];
                    const float dist = __builtin_fmaf(-2.f, ssum, ev[r]);
                    const float hi   = fmaxf(m1[rg], dist);
                    m2[rg] = fminf(m2[rg], hi);
                    i1[rg] = (dist < m1[rg]) ? (gct * 16 + lq * 4 + r) : i1[rg];
                    m1[rg] = fminf(m1[rg], dist);
                }
            }
        }

        // ...and land them in the other buffer AFTER compute (loads flew in parallel)
        if (pre) {
#pragma unroll
            for (int r = 0; r < 4; ++r) {
                const int o   = r * 4096 + tid * 16;
                const int row = o >> 8;
                const int c16 = (o >> 4) & 15;
                const int so  = (o & ~255) | ((c16 ^ (row & 7)) << 4);
                *(f32x4*)((char*)s_cb[cur ^ 1] + so) = stg[r];
            }
        }
        __syncthreads();
        cur ^= 1;
    }

    // merge top-2 across the 4 k-quarters (lanes xor 16, 32); ties across
    // quarters force m2<=m1 -> flagged -> exact slow path (validated)
#pragma unroll
    for (int rg = 0; rg < 2; ++rg) {
#pragma unroll
        for (int mk = 16; mk <= 32; mk <<= 1) {
            const float om1 = __shfl_xor(m1[rg], mk, 64);
            const float om2 = __shfl_xor(m2[rg], mk, 64);
            const int   oi  = __shfl_xor(i1[rg], mk, 64);
            const float hi  = fmaxf(m1[rg], om1);
            m2[rg] = fminf(fminf(m2[rg], om2), hi);
            i1[rg] = (om1 < m1[rg]) ? oi : i1[rg];
            m1[rg] = fminf(m1[rg], om1);
        }
    }

#pragma unroll
    for (int rg = 0; rg < 2; ++rg) {
        const bool flagged = (m2[rg] <= m1[rg] + MU);
        if (lane < 16 && !flagged) s_win[wid * 32 + rg * 16 + l15] = i1[rg];

        unsigned long long fmask = __ballot(flagged) & 0xFFFFull;

        // slow path: bit-exact full scan for ambiguous rows, wave-cooperative
        while (fmask) {
            const int R = __builtin_ctzll(fmask);
            fmask &= fmask - 1;
            const int n = rowbase + rg * 16 + R;
            const float* zq = zin + (size_t)(n >> 12) * (D_DIM * HW) + (n & (HW - 1));

            float zz = 0.f;                         // sequential, separate rounding
            for (int d = 0; d < D_DIM; ++d) {
                const float v = zq[(size_t)d * HW]; // same addr all lanes -> broadcast
                const float q = v * v; zz = zz + q;
            }
            const int k0 = lane * 8;
            float dot[8];
#pragma unroll
            for (int j = 0; j < 8; ++j) dot[j] = 0.f;
            for (int d = 0; d < D_DIM; ++d) {
                const float zd = zq[(size_t)d * HW];
#pragma unroll
                for (int j = 0; j < 8; ++j)
                    dot[j] = __builtin_fmaf(emb[(size_t)(k0 + j) * D_DIM + d], zd, dot[j]);
            }
            float bd = 3.4e38f; int bidx = 0;
#pragma unroll
            for (int j = 0; j < 8; ++j) {
                const float mm = 2.0f * dot[j];
                const float s  = zz - mm;
                const float dist = s + s_ee[k0 + j];
                if (dist < bd) { bd = dist; bidx = k0 + j; }
            }
#pragma unroll
            for (int mk = 1; mk <= 32; mk <<= 1) {  // lexicographic (dist, idx) min
                const float od = __shfl_xor(bd, mk, 64);
                const int   oi = __shfl_xor(bidx, mk, 64);
                const bool take = (od < bd) || (od == bd && oi < bidx);
                bd   = take ? od : bd;
                bidx = take ? oi : bidx;
            }
            if (lane == 0) s_win[wid * 32 + rg * 16 + R] = bidx;
        }
    }
    __syncthreads();

    // epilogue: gather + coalesced write of both outputs (128 rows x 64 d)
    const int drow = tid & 127;
    const int dh   = tid >> 7;                  // d-half 0/1
    const int n2   = blockIdx.x * RPB + drow;
    float* o1 = out + (size_t)(n2 >> 12) * (D_DIM * HW) + (n2 & (HW - 1));
    float* o2 = o1 + HALF;
    const float* wv = emb + (size_t)s_win[drow] * D_DIM;
#pragma unroll
    for (int dd = 0; dd < 32; ++dd) {
        const int d = dh * 32 + dd;
        const float v = wv[d];
        o1[(size_t)d * HW] = v;
        o2[(size_t)d * HW] = v;
    }
}

// fallback (validated round-2 kernel) if ws too small
__global__ __launch_bounds__(256) void vq_fallback(const float* __restrict__ zin,
                                                   const float* __restrict__ emb,
                                                   float* __restrict__ out) {
#pragma clang fp contract(off)
    __shared__ float s_ee[K_CODES];
    const int tid = threadIdx.x;
    for (int k = tid; k < K_CODES; k += 256) {
        const float* w = emb + k * D_DIM;
        float acc = 0.f;
        for (int d = 0; d < D_DIM; ++d) { float q = w[d] * w[d]; acc = acc + q; }
        s_ee[k] = acc;
    }
    __syncthreads();
    const int n = blockIdx.x * 256 + tid;
    const int b = n >> 12;
    const int p = n & (HW - 1);
    const float* zp = zin + (size_t)b * (D_DIM * HW) + p;
    float zr[D_DIM];
#pragma unroll
    for (int d = 0; d < D_DIM; ++d) zr[d] = zp[(size_t)d * HW];
    float zz = 0.f;
#pragma unroll
    for (int d = 0; d < D_DIM; ++d) { float q = zr[d] * zr[d]; zz = zz + q; }
    float best = 3.4e38f; int bi = 0;
    for (int k0 = 0; k0 < K_CODES; k0 += 8) {
        const float* w = emb + (size_t)k0 * D_DIM;
        float dot[8];
#pragma unroll
        for (int j = 0; j < 8; ++j) dot[j] = 0.f;
#pragma unroll
        for (int d = 0; d < D_DIM; ++d) {
            const float z = zr[d];
#pragma unroll
            for (int j = 0; j < 8; ++j)
                dot[j] = __builtin_fmaf(w[j * D_DIM + d], z, dot[j]);
        }
#pragma unroll
        for (int j = 0; j < 8; ++j) {
            const float m = 2.0f * dot[j];
            const float s = zz - m;
            const float dist = s + s_ee[k0 + j];
            if (dist < best) { best = dist; bi = k0 + j; }
        }
    }
    const float* wb = emb + (size_t)bi * D_DIM;
    float* o1 = out + (size_t)b * (D_DIM * HW) + p;
    float* o2 = o1 + HALF;
#pragma unroll
    for (int d = 0; d < D_DIM; ++d) {
        const float v = wb[d];
        o1[(size_t)d * HW] = v;
        o2[(size_t)d * HW] = v;
    }
}

extern "C" void kernel_launch(void* const* d_in, const int* in_sizes, int n_in,
                              void* d_out, int out_size, void* d_ws, size_t ws_size,
                              hipStream_t stream) {
    const float* z   = (const float*)d_in[0];
    const float* emb = (const float*)d_in[1];
    float* out = (float*)d_out;

    const size_t need = 2048 + (size_t)K_CODES * 128 * sizeof(unsigned short);
    if (ws_size >= need) {
        float* ee = (float*)d_ws;
        unsigned short* ehl = (unsigned short*)((char*)d_ws + 2048);
        hipLaunchKernelGGL(prep, dim3(2), dim3(256), 0, stream, emb, ee, ehl);
        hipLaunchKernelGGL(vq_top2, dim3(N_ROWS / RPB), dim3(256), 0, stream,
                           z, emb, ee, ehl, out);
    } else {
        hipLaunchKernelGGL(vq_fallback, dim3(N_ROWS / 256), dim3(256), 0, stream,
                           z, emb, out);
    }
}

// Round 12
// 108.728 us; speedup vs baseline: 1.9018x; 1.5428x over previous
//
#include <hip/hip_runtime.h>

constexpr int K_CODES = 512;
constexpr int D_DIM   = 64;
constexpr int HW      = 4096;               // 64*64
constexpr int BATCH   = 32;
constexpr int N_ROWS  = BATCH * HW;         // 131072
constexpr int HALF    = BATCH * D_DIM * HW; // elements per output tensor
constexpr float MU    = 1e-4f;              // 5x over ~1.9e-5 approx-vs-ref spread
constexpr int TPB     = 1024;               // 16 waves
constexpr int RPB     = 512;                // rows per block (16 waves x 32)

typedef __attribute__((ext_vector_type(8))) short bf16x8;
typedef __attribute__((ext_vector_type(4))) float f32x4;

__device__ __forceinline__ unsigned short f32_bf16_rn(float x) {
    unsigned u = __builtin_bit_cast(unsigned, x);
    unsigned r = (u + 0x7FFFu + ((u >> 16) & 1u)) >> 16;   // round-to-nearest-even
    return (unsigned short)r;
}
__device__ __forceinline__ float bf16_f32(unsigned short h) {
    unsigned u = ((unsigned)h) << 16;
    return __builtin_bit_cast(float, u);
}

// prep: ee[k]=|e_k|^2 (bit-exact sequential f32, = reference) and interleaved
// two-term bf16 codebook: ehl[k*128 + d] = hi, ehl[k*128 + 64 + d] = lo
__global__ void prep(const float* __restrict__ emb, float* __restrict__ ee,
                     unsigned short* __restrict__ ehl) {
#pragma clang fp contract(off)
    int k = blockIdx.x * 256 + threadIdx.x;
    if (k >= K_CODES) return;
    const float* w = emb + k * D_DIM;
    float acc = 0.f;
    for (int d = 0; d < D_DIM; ++d) {
        float v = w[d];
        float q = v * v; acc = acc + q;
        unsigned short h = f32_bf16_rn(v);
        ehl[k * 128 + d]      = h;
        ehl[k * 128 + 64 + d] = f32_bf16_rn(v - bf16_f32(h));
    }
    ee[k] = acc;
}

// Persistent-codebook block: 1024 thr = 16 waves, grid 256 (1 block/CU).
// Whole split codebook (128 KB) staged to LDS ONCE (swizzled), then each wave
// independently scans its 32 rows x 512 codes -- no barriers, no re-staging.
// Single-pass per-row top-2 via 16x16x32 bf16 MFMA, two-term z/e split
// (numerics byte-identical to rounds 10-11, absmax 0.0).
// gap > MU: approx argmin provably == reference argmin. Else: wave-cooperative
// bit-exact 512-code scan (validated recipe).
__global__ __launch_bounds__(TPB, 4) void vq_persist(const float* __restrict__ zin,
                                                     const float* __restrict__ emb,
                                                     const float* __restrict__ ee,
                                                     const unsigned short* __restrict__ ehl,
                                                     float* __restrict__ out) {
#pragma clang fp contract(off)
    __shared__ __attribute__((aligned(16))) short s_cb[K_CODES * 128]; // 128 KB
    __shared__ __attribute__((aligned(16))) float s_ee[K_CODES];       // 2 KB

    const int tid  = threadIdx.x;
    const int wid  = tid >> 6;           // 0..15
    const int lane = tid & 63;
    const int l15  = lane & 15;
    const int lq   = lane >> 4;          // 0..3 = k-quarter

    // ---- stage whole codebook, swizzled: logical byte o (row=o>>8, c16=(o>>4)&15)
    // lands at (o & ~255) | ((c16 ^ (row&7)) << 4). 8 x 16B per thread.
#pragma unroll
    for (int r = 0; r < 8; ++r) {
        const int o = r * (TPB * 16) + tid * 16;
        const f32x4 v = *(const f32x4*)((const char*)ehl + o);
        const int row = o >> 8;
        const int c16 = (o >> 4) & 15;
        const int so  = (o & ~255) | ((c16 ^ (row & 7)) << 4);
        *(f32x4*)((char*)s_cb + so) = v;
    }
    if (tid < K_CODES) s_ee[tid] = ee[tid];
    __syncthreads();                     // the only barrier

    const int rowbase = blockIdx.x * RPB + wid * 32;

    // ---- z B-fragments for 2 rowgroups (layout validated rounds 7-11):
    // col = l15, k = s*32 + lq*8 + j
    bf16x8 zh[2][2], zl[2][2];
#pragma unroll
    for (int rg = 0; rg < 2; ++rg) {
        const int n0 = rowbase + rg * 16 + l15;
        const float* zp = zin + (size_t)(n0 >> 12) * (D_DIM * HW) + (n0 & (HW - 1));
#pragma unroll
        for (int s = 0; s < 2; ++s) {
            float rz[8];
#pragma unroll
            for (int j = 0; j < 8; ++j)
                rz[j] = zp[(size_t)(s * 32 + lq * 8 + j) * HW];
#pragma unroll
            for (int j = 0; j < 8; ++j) {
                unsigned short h = f32_bf16_rn(rz[j]);
                zh[rg][s][j] = (short)h;
                zl[rg][s][j] = (short)f32_bf16_rn(rz[j] - bf16_f32(h));
            }
        }
    }

    // per-lane swizzled fragment byte offsets: row = gct*16+l15 (256 B/row),
    // col16 = h*8 + s*4 + lq, swizzled by row&7 = l15&7
    int fb[4];
#pragma unroll
    for (int h = 0; h < 2; ++h)
#pragma unroll
        for (int s = 0; s < 2; ++s)
            fb[h * 2 + s] = l15 * 256 + (((h * 8 + s * 4 + lq) ^ (l15 & 7)) << 4);

    float m1[2] = {3.4e38f, 3.4e38f}, m2[2] = {3.4e38f, 3.4e38f};
    int   i1[2] = {0, 0};

#pragma unroll 2
    for (int gct = 0; gct < 32; ++gct) {
        const char* cb = (const char*)s_cb + gct * 4096;
        const bf16x8 ah0 = *(const bf16x8*)(cb + fb[0]);
        const bf16x8 ah1 = *(const bf16x8*)(cb + fb[1]);
        const bf16x8 al0 = *(const bf16x8*)(cb + fb[2]);
        const bf16x8 al1 = *(const bf16x8*)(cb + fb[3]);
        const f32x4 ev = *(const f32x4*)&s_ee[gct * 16 + lq * 4];
#pragma unroll
        for (int rg = 0; rg < 2; ++rg) {
            f32x4 a0 = {0.f,0.f,0.f,0.f}, a1 = {0.f,0.f,0.f,0.f}, a2 = {0.f,0.f,0.f,0.f};
            a0 = __builtin_amdgcn_mfma_f32_16x16x32_bf16(ah0, zh[rg][0], a0, 0, 0, 0);
            a1 = __builtin_amdgcn_mfma_f32_16x16x32_bf16(al0, zh[rg][0], a1, 0, 0, 0);
            a2 = __builtin_amdgcn_mfma_f32_16x16x32_bf16(ah0, zl[rg][0], a2, 0, 0, 0);
            a0 = __builtin_amdgcn_mfma_f32_16x16x32_bf16(ah1, zh[rg][1], a0, 0, 0, 0);
            a1 = __builtin_amdgcn_mfma_f32_16x16x32_bf16(al1, zh[rg][1], a1, 0, 0, 0);
            a2 = __builtin_amdgcn_mfma_f32_16x16x32_bf16(ah1, zl[rg][1], a2, 0, 0, 0);
#pragma unroll
            for (int r = 0; r < 4; ++r) {
                const float ssum = (a0[r] + a1[r]) + a2[r];
                const float dist = __builtin_fmaf(-2.f, ssum, ev[r]);
                const float hi   = fmaxf(m1[rg], dist);
                m2[rg] = fminf(m2[rg], hi);
                i1[rg] = (dist < m1[rg]) ? (gct * 16 + lq * 4 + r) : i1[rg];
                m1[rg] = fminf(m1[rg], dist);
            }
        }
    }

    // merge top-2 across the 4 k-quarters; afterwards every lane holds the
    // final (m1,i1,m2) for row rg*16 + l15
#pragma unroll
    for (int rg = 0; rg < 2; ++rg) {
#pragma unroll
        for (int mk = 16; mk <= 32; mk <<= 1) {
            const float om1 = __shfl_xor(m1[rg], mk, 64);
            const float om2 = __shfl_xor(m2[rg], mk, 64);
            const int   oi  = __shfl_xor(i1[rg], mk, 64);
            const float hi  = fmaxf(m1[rg], om1);
            m2[rg] = fminf(fminf(m2[rg], om2), hi);
            i1[rg] = (om1 < m1[rg]) ? oi : i1[rg];
            m1[rg] = fminf(m1[rg], om1);
        }
    }

    int w[2] = {i1[0], i1[1]};           // winner per (rg, l15), kept in registers

#pragma unroll
    for (int rg = 0; rg < 2; ++rg) {
        const bool flagged = (m2[rg] <= m1[rg] + MU);
        unsigned long long fmask = __ballot(flagged) & 0xFFFFull;

        // slow path: bit-exact full scan for ambiguous rows, wave-cooperative
        while (fmask) {
            const int R = __builtin_ctzll(fmask);
            fmask &= fmask - 1;
            const int n = rowbase + rg * 16 + R;
            const float* zq = zin + (size_t)(n >> 12) * (D_DIM * HW) + (n & (HW - 1));

            float zz = 0.f;                         // sequential, separate rounding
            for (int d = 0; d < D_DIM; ++d) {
                const float v = zq[(size_t)d * HW]; // same addr all lanes -> broadcast
                const float q = v * v; zz = zz + q;
            }
            const int k0 = lane * 8;
            float dot[8];
#pragma unroll
            for (int j = 0; j < 8; ++j) dot[j] = 0.f;
            for (int d = 0; d < D_DIM; ++d) {
                const float zd = zq[(size_t)d * HW];
#pragma unroll
                for (int j = 0; j < 8; ++j)
                    dot[j] = __builtin_fmaf(emb[(size_t)(k0 + j) * D_DIM + d], zd, dot[j]);
            }
            float bd = 3.4e38f; int bidx = 0;
#pragma unroll
            for (int j = 0; j < 8; ++j) {
                const float mm = 2.0f * dot[j];
                const float s  = zz - mm;
                const float dist = s + s_ee[k0 + j];
                if (dist < bd) { bd = dist; bidx = k0 + j; }
            }
#pragma unroll
            for (int mk = 1; mk <= 32; mk <<= 1) {  // lexicographic (dist, idx) min
                const float od = __shfl_xor(bd, mk, 64);
                const int   oi = __shfl_xor(bidx, mk, 64);
                const bool take = (od < bd) || (od == bd && oi < bidx);
                bd   = take ? od : bd;
                bidx = take ? oi : bidx;
            }
            if ((lane & 15) == R) w[rg] = bidx;     // bidx uniform across wave
        }
    }

    // ---- epilogue (per-wave, no sync): lane covers row = lane&31 at
    // d-half lane>>5. Winner for that row is in this lane's w[(lane>>4)&1].
    const int myrow = lane & 31;
    const int win   = w[(lane >> 4) & 1];
    const int n2    = rowbase + myrow;
    const int d0    = (lane >> 5) * 32;
    float* o1 = out + (size_t)(n2 >> 12) * (D_DIM * HW) + (n2 & (HW - 1));
    float* o2 = o1 + HALF;
    const float* wv = emb + (size_t)win * D_DIM + d0;
#pragma unroll
    for (int q = 0; q < 8; ++q) {
        const f32x4 v = *(const f32x4*)(wv + q * 4);
#pragma unroll
        for (int i = 0; i < 4; ++i) {
            const int d = d0 + q * 4 + i;
            o1[(size_t)d * HW] = v[i];
            o2[(size_t)d * HW] = v[i];
        }
    }
}

// fallback (validated round-2 kernel) if ws too small
__global__ __launch_bounds__(256) void vq_fallback(const float* __restrict__ zin,
                                                   const float* __restrict__ emb,
                                                   float* __restrict__ out) {
#pragma clang fp contract(off)
    __shared__ float s_ee[K_CODES];
    const int tid = threadIdx.x;
    for (int k = tid; k < K_CODES; k += 256) {
        const float* w = emb + k * D_DIM;
        float acc = 0.f;
        for (int d = 0; d < D_DIM; ++d) { float q = w[d] * w[d]; acc = acc + q; }
        s_ee[k] = acc;
    }
    __syncthreads();
    const int n = blockIdx.x * 256 + tid;
    const int b = n >> 12;
    const int p = n & (HW - 1);
    const float* zp = zin + (size_t)b * (D_DIM * HW) + p;
    float zr[D_DIM];
#pragma unroll
    for (int d = 0; d < D_DIM; ++d) zr[d] = zp[(size_t)d * HW];
    float zz = 0.f;
#pragma unroll
    for (int d = 0; d < D_DIM; ++d) { float q = zr[d] * zr[d]; zz = zz + q; }
    float best = 3.4e38f; int bi = 0;
    for (int k0 = 0; k0 < K_CODES; k0 += 8) {
        const float* w = emb + (size_t)k0 * D_DIM;
        float dot[8];
#pragma unroll
        for (int j = 0; j < 8; ++j) dot[j] = 0.f;
#pragma unroll
        for (int d = 0; d < D_DIM; ++d) {
            const float z = zr[d];
#pragma unroll
            for (int j = 0; j < 8; ++j)
                dot[j] = __builtin_fmaf(w[j * D_DIM + d], z, dot[j]);
        }
#pragma unroll
        for (int j = 0; j < 8; ++j) {
            const float m = 2.0f * dot[j];
            const float s = zz - m;
            const float dist = s + s_ee[k0 + j];
            if (dist < best) { best = dist; bi = k0 + j; }
        }
    }
    const float* wb = emb + (size_t)bi * D_DIM;
    float* o1 = out + (size_t)b * (D_DIM * HW) + p;
    float* o2 = o1 + HALF;
#pragma unroll
    for (int d = 0; d < D_DIM; ++d) {
        const float v = wb[d];
        o1[(size_t)d * HW] = v;
        o2[(size_t)d * HW] = v;
    }
}

extern "C" void kernel_launch(void* const* d_in, const int* in_sizes, int n_in,
                              void* d_out, int out_size, void* d_ws, size_t ws_size,
                              hipStream_t stream) {
    const float* z   = (const float*)d_in[0];
    const float* emb = (const float*)d_in[1];
    float* out = (float*)d_out;

    const size_t need = 2048 + (size_t)K_CODES * 128 * sizeof(unsigned short);
    if (ws_size >= need) {
        float* ee = (float*)d_ws;
        unsigned short* ehl = (unsigned short*)((char*)d_ws + 2048);
        hipLaunchKernelGGL(prep, dim3(2), dim3(256), 0, stream, emb, ee, ehl);
        hipLaunchKernelGGL(vq_persist, dim3(N_ROWS / RPB), dim3(TPB), 0, stream,
                           z, emb, ee, ehl, out);
    } else {
        hipLaunchKernelGGL(vq_fallback, dim3(N_ROWS / 256), dim3(256), 0, stream,
                           z, emb, out);
    }
}

// Round 14
// 66.290 us; speedup vs baseline: 3.1192x; 1.6402x over previous
//
#include <hip/hip_runtime.h>

constexpr int K_CODES = 512;
constexpr int D_DIM   = 64;
constexpr int HW      = 4096;               // 64*64
constexpr int BATCH   = 32;
constexpr int N_ROWS  = BATCH * HW;         // 131072
constexpr int HALF    = BATCH * D_DIM * HW; // elements per output tensor
constexpr float MU    = 1e-4f;              // 5x over ~1.9e-5 approx-vs-ref spread
constexpr int TPB     = 1024;               // 16 waves
constexpr int RPB     = 512;                // rows per block (16 waves x 32)

typedef __attribute__((ext_vector_type(8))) short bf16x8;
typedef __attribute__((ext_vector_type(4))) float f32x4;

__device__ __forceinline__ unsigned short f32_bf16_rn(float x) {
    unsigned u = __builtin_bit_cast(unsigned, x);
    unsigned r = (u + 0x7FFFu + ((u >> 16) & 1u)) >> 16;   // round-to-nearest-even
    return (unsigned short)r;
}
__device__ __forceinline__ float bf16_f32(unsigned short h) {
    unsigned u = ((unsigned)h) << 16;
    return __builtin_bit_cast(float, u);
}

// prep: ee[k]=|e_k|^2 (bit-exact sequential f32, = reference), interleaved
// two-term bf16 codebook ehl[k*128 + d]=hi, [.. +64+d]=lo, and transposed
// f32 codebook embT[d*512 + k] (for the coalesced exact slow path).
__global__ void prep(const float* __restrict__ emb, float* __restrict__ ee,
                     unsigned short* __restrict__ ehl, float* __restrict__ embT) {
#pragma clang fp contract(off)
    int k = blockIdx.x * 256 + threadIdx.x;
    if (k >= K_CODES) return;
    const float* w = emb + k * D_DIM;
    float acc = 0.f;
    for (int d = 0; d < D_DIM; ++d) {
        float v = w[d];
        float q = v * v; acc = acc + q;
        unsigned short h = f32_bf16_rn(v);
        ehl[k * 128 + d]      = h;
        ehl[k * 128 + 64 + d] = f32_bf16_rn(v - bf16_f32(h));
        embT[d * K_CODES + k] = v;
    }
    ee[k] = acc;
}

// ROUND-12 STRUCTURE VERBATIM (passed both validations, 108.7 us) with ONE
// change: the slow path now reads the TRANSPOSED codebook coalesced
// (lane L owns codes L*8+j; two f32x4 loads per d). Round 12's wall was the
// old slow path's 64-lines-per-instruction emb gather (~10+ us per flagged
// row; ~1% rows flagged -> 50-70 us serial tail, VALUBusy 22%).
// Numerics byte-identical: single-pass per-row top-2 via 16x16x32 bf16 MFMA,
// two-term z/e split, MU-gap certificate, bit-exact f32 slow-path recipe
// (sequential zz, d-ascending fma chain, first-occurrence argmin).
__global__ __launch_bounds__(TPB, 4) void vq_persist(const float* __restrict__ zin,
                                                     const float* __restrict__ emb,
                                                     const float* __restrict__ ee,
                                                     const unsigned short* __restrict__ ehl,
                                                     const float* __restrict__ embT,
                                                     float* __restrict__ out) {
#pragma clang fp contract(off)
    __shared__ __attribute__((aligned(16))) short s_cb[K_CODES * 128]; // 128 KB
    __shared__ __attribute__((aligned(16))) float s_ee[K_CODES];       // 2 KB

    const int tid  = threadIdx.x;
    const int wid  = tid >> 6;           // 0..15
    const int lane = tid & 63;
    const int l15  = lane & 15;
    const int lq   = lane >> 4;          // 0..3 = k-quarter

    // ---- stage whole codebook, swizzled: logical byte o (row=o>>8, c16=(o>>4)&15)
    // lands at (o & ~255) | ((c16 ^ (row&7)) << 4). 8 x 16B per thread.
#pragma unroll
    for (int r = 0; r < 8; ++r) {
        const int o = r * (TPB * 16) + tid * 16;
        const f32x4 v = *(const f32x4*)((const char*)ehl + o);
        const int row = o >> 8;
        const int c16 = (o >> 4) & 15;
        const int so  = (o & ~255) | ((c16 ^ (row & 7)) << 4);
        *(f32x4*)((char*)s_cb + so) = v;
    }
    if (tid < K_CODES) s_ee[tid] = ee[tid];
    __syncthreads();                     // the only barrier

    const int rowbase = blockIdx.x * RPB + wid * 32;

    // ---- z B-fragments for 2 rowgroups (layout validated rounds 7-12):
    // col = l15, k = s*32 + lq*8 + j
    bf16x8 zh[2][2], zl[2][2];
#pragma unroll
    for (int rg = 0; rg < 2; ++rg) {
        const int n0 = rowbase + rg * 16 + l15;
        const float* zp = zin + (size_t)(n0 >> 12) * (D_DIM * HW) + (n0 & (HW - 1));
#pragma unroll
        for (int s = 0; s < 2; ++s) {
            float rz[8];
#pragma unroll
            for (int j = 0; j < 8; ++j)
                rz[j] = zp[(size_t)(s * 32 + lq * 8 + j) * HW];
#pragma unroll
            for (int j = 0; j < 8; ++j) {
                unsigned short h = f32_bf16_rn(rz[j]);
                zh[rg][s][j] = (short)h;
                zl[rg][s][j] = (short)f32_bf16_rn(rz[j] - bf16_f32(h));
            }
        }
    }

    // per-lane swizzled fragment byte offsets: row = gct*16+l15 (256 B/row),
    // col16 = h*8 + s*4 + lq, swizzled by row&7 = l15&7
    int fb[4];
#pragma unroll
    for (int h = 0; h < 2; ++h)
#pragma unroll
        for (int s = 0; s < 2; ++s)
            fb[h * 2 + s] = l15 * 256 + (((h * 8 + s * 4 + lq) ^ (l15 & 7)) << 4);

    float m1[2] = {3.4e38f, 3.4e38f}, m2[2] = {3.4e38f, 3.4e38f};
    int   i1[2] = {0, 0};

#pragma unroll 2
    for (int gct = 0; gct < 32; ++gct) {
        const char* cb = (const char*)s_cb + gct * 4096;
        const bf16x8 ah0 = *(const bf16x8*)(cb + fb[0]);
        const bf16x8 ah1 = *(const bf16x8*)(cb + fb[1]);
        const bf16x8 al0 = *(const bf16x8*)(cb + fb[2]);
        const bf16x8 al1 = *(const bf16x8*)(cb + fb[3]);
        const f32x4 ev = *(const f32x4*)&s_ee[gct * 16 + lq * 4];
#pragma unroll
        for (int rg = 0; rg < 2; ++rg) {
            f32x4 a0 = {0.f,0.f,0.f,0.f}, a1 = {0.f,0.f,0.f,0.f}, a2 = {0.f,0.f,0.f,0.f};
            a0 = __builtin_amdgcn_mfma_f32_16x16x32_bf16(ah0, zh[rg][0], a0, 0, 0, 0);
            a1 = __builtin_amdgcn_mfma_f32_16x16x32_bf16(al0, zh[rg][0], a1, 0, 0, 0);
            a2 = __builtin_amdgcn_mfma_f32_16x16x32_bf16(ah0, zl[rg][0], a2, 0, 0, 0);
            a0 = __builtin_amdgcn_mfma_f32_16x16x32_bf16(ah1, zh[rg][1], a0, 0, 0, 0);
            a1 = __builtin_amdgcn_mfma_f32_16x16x32_bf16(al1, zh[rg][1], a1, 0, 0, 0);
            a2 = __builtin_amdgcn_mfma_f32_16x16x32_bf16(ah1, zl[rg][1], a2, 0, 0, 0);
#pragma unroll
            for (int r = 0; r < 4; ++r) {
                const float ssum = (a0[r] + a1[r]) + a2[r];
                const float dist = __builtin_fmaf(-2.f, ssum, ev[r]);
                const float hi   = fmaxf(m1[rg], dist);
                m2[rg] = fminf(m2[rg], hi);
                i1[rg] = (dist < m1[rg]) ? (gct * 16 + lq * 4 + r) : i1[rg];
                m1[rg] = fminf(m1[rg], dist);
            }
        }
    }

    // merge top-2 across the 4 k-quarters; afterwards every lane holds the
    // final (m1,i1,m2) for row rg*16 + l15
#pragma unroll
    for (int rg = 0; rg < 2; ++rg) {
#pragma unroll
        for (int mk = 16; mk <= 32; mk <<= 1) {
            const float om1 = __shfl_xor(m1[rg], mk, 64);
            const float om2 = __shfl_xor(m2[rg], mk, 64);
            const int   oi  = __shfl_xor(i1[rg], mk, 64);
            const float hi  = fmaxf(m1[rg], om1);
            m2[rg] = fminf(fminf(m2[rg], om2), hi);
            i1[rg] = (om1 < m1[rg]) ? oi : i1[rg];
            m1[rg] = fminf(m1[rg], om1);
        }
    }

    int w[2] = {i1[0], i1[1]};           // winner per (rg, l15), kept in registers

#pragma unroll
    for (int rg = 0; rg < 2; ++rg) {
        const bool flagged = (m2[rg] <= m1[rg] + MU);
        unsigned long long fmask = __ballot(flagged) & 0xFFFFull;

        // slow path: bit-exact full scan for ambiguous rows, wave-cooperative.
        // Lane L owns codes L*8+j; embT reads fully coalesced (f32x4 pairs).
        while (fmask) {
            const int R = __builtin_ctzll(fmask);
            fmask &= fmask - 1;
            const int n = rowbase + rg * 16 + R;
            const float* zq = zin + (size_t)(n >> 12) * (D_DIM * HW) + (n & (HW - 1));

            float zz = 0.f;                         // sequential, separate rounding
            for (int d = 0; d < D_DIM; ++d) {
                const float v = zq[(size_t)d * HW]; // wave-uniform addr -> s_load
                const float q = v * v; zz = zz + q;
            }
            float dot[8];
#pragma unroll
            for (int j = 0; j < 8; ++j) dot[j] = 0.f;
            for (int d = 0; d < D_DIM; ++d) {
                const float zd = zq[(size_t)d * HW];
                const float* er = embT + d * K_CODES + lane * 8;
                const f32x4 e0 = *(const f32x4*)(er);
                const f32x4 e1 = *(const f32x4*)(er + 4);
#pragma unroll
                for (int j = 0; j < 4; ++j) {
                    dot[j]     = __builtin_fmaf(e0[j], zd, dot[j]);
                    dot[j + 4] = __builtin_fmaf(e1[j], zd, dot[j + 4]);
                }
            }
            float bd = 3.4e38f; int bidx = 0;
#pragma unroll
            for (int j = 0; j < 8; ++j) {
                const float mm = 2.0f * dot[j];
                const float s  = zz - mm;
                const float dist = s + s_ee[lane * 8 + j];
                if (dist < bd) { bd = dist; bidx = lane * 8 + j; }  // strict < : lowest j
            }
#pragma unroll
            for (int mk = 1; mk <= 32; mk <<= 1) {  // lexicographic (dist, idx) min
                const float od = __shfl_xor(bd, mk, 64);
                const int   oi = __shfl_xor(bidx, mk, 64);
                const bool take = (od < bd) || (od == bd && oi < bidx);
                bd   = take ? od : bd;
                bidx = take ? oi : bidx;
            }
            if ((lane & 15) == R) w[rg] = bidx;     // bidx uniform across wave
        }
    }

    // ---- epilogue (per-wave, no sync): lane covers row = lane&31 at
    // d-half lane>>5. Winner for that row is in this lane's w[(lane>>4)&1].
    const int myrow = lane & 31;
    const int win   = w[(lane >> 4) & 1];
    const int n2    = rowbase + myrow;
    const int d0    = (lane >> 5) * 32;
    float* o1 = out + (size_t)(n2 >> 12) * (D_DIM * HW) + (n2 & (HW - 1));
    float* o2 = o1 + HALF;
    const float* wv = emb + (size_t)win * D_DIM + d0;
#pragma unroll
    for (int q = 0; q < 8; ++q) {
        const f32x4 v = *(const f32x4*)(wv + q * 4);
#pragma unroll
        for (int i = 0; i < 4; ++i) {
            const int d = d0 + q * 4 + i;
            o1[(size_t)d * HW] = v[i];
            o2[(size_t)d * HW] = v[i];
        }
    }
}

// fallback (validated round-2 kernel) if ws too small
__global__ __launch_bounds__(256) void vq_fallback(const float* __restrict__ zin,
                                                   const float* __restrict__ emb,
                                                   float* __restrict__ out) {
#pragma clang fp contract(off)
    __shared__ float s_ee[K_CODES];
    const int tid = threadIdx.x;
    for (int k = tid; k < K_CODES; k += 256) {
        const float* w = emb + k * D_DIM;
        float acc = 0.f;
        for (int d = 0; d < D_DIM; ++d) { float q = w[d] * w[d]; acc = acc + q; }
        s_ee[k] = acc;
    }
    __syncthreads();
    const int n = blockIdx.x * 256 + tid;
    const int b = n >> 12;
    const int p = n & (HW - 1);
    const float* zp = zin + (size_t)b * (D_DIM * HW) + p;
    float zr[D_DIM];
#pragma unroll
    for (int d = 0; d < D_DIM; ++d) zr[d] = zp[(size_t)d * HW];
    float zz = 0.f;
#pragma unroll
    for (int d = 0; d < D_DIM; ++d) { float q = zr[d] * zr[d]; zz = zz + q; }
    float best = 3.4e38f; int bi = 0;
    for (int k0 = 0; k0 < K_CODES; k0 += 8) {
        const float* w = emb + (size_t)k0 * D_DIM;
        float dot[8];
#pragma unroll
        for (int j = 0; j < 8; ++j) dot[j] = 0.f;
#pragma unroll
        for (int d = 0; d < D_DIM; ++d) {
            const float z = zr[d];
#pragma unroll
            for (int j = 0; j < 8; ++j)
                dot[j] = __builtin_fmaf(w[j * D_DIM + d], z, dot[j]);
        }
#pragma unroll
        for (int j = 0; j < 8; ++j) {
            const float m = 2.0f * dot[j];
            const float s = zz - m;
            const float dist = s + s_ee[k0 + j];
            if (dist < best) { best = dist; bi = k0 + j; }
        }
    }
    const float* wb = emb + (size_t)bi * D_DIM;
    float* o1 = out + (size_t)b * (D_DIM * HW) + p;
    float* o2 = o1 + HALF;
#pragma unroll
    for (int d = 0; d < D_DIM; ++d) {
        const float v = wb[d];
        o1[(size_t)d * HW] = v;
        o2[(size_t)d * HW] = v;
    }
}

extern "C" void kernel_launch(void* const* d_in, const int* in_sizes, int n_in,
                              void* d_out, int out_size, void* d_ws, size_t ws_size,
                              hipStream_t stream) {
    const float* z   = (const float*)d_in[0];
    const float* emb = (const float*)d_in[1];
    float* out = (float*)d_out;

    const size_t EHL_B  = (size_t)K_CODES * 128 * sizeof(unsigned short); // 128 KB
    const size_t EMBT_B = (size_t)K_CODES * D_DIM * sizeof(float);        // 128 KB
    const size_t need = 2048 + EHL_B + EMBT_B;                            // 258 KB
    if (ws_size >= need) {
        float* ee = (float*)d_ws;
        unsigned short* ehl = (unsigned short*)((char*)d_ws + 2048);
        float* embT = (float*)((char*)d_ws + 2048 + EHL_B);
        hipLaunchKernelGGL(prep, dim3(2), dim3(256), 0, stream, emb, ee, ehl, embT);
        hipLaunchKernelGGL(vq_persist, dim3(N_ROWS / RPB), dim3(TPB), 0, stream,
                           z, emb, ee, ehl, embT, out);
    } else {
        hipLaunchKernelGGL(vq_fallback, dim3(N_ROWS / 256), dim3(256), 0, stream,
                           z, emb, out);
    }
}

// Round 15
// 65.698 us; speedup vs baseline: 3.1473x; 1.0090x over previous
//
#include <hip/hip_runtime.h>

constexpr int K_CODES = 512;
constexpr int D_DIM   = 64;
constexpr int HW      = 4096;               // 64*64
constexpr int BATCH   = 32;
constexpr int N_ROWS  = BATCH * HW;         // 131072
constexpr int HALF    = BATCH * D_DIM * HW; // elements per output tensor
constexpr float MU    = 1e-4f;              // 5x over ~1.9e-5 approx-vs-ref spread
constexpr int TPB     = 1024;               // 16 waves
constexpr int RPB     = 512;                // rows per block (16 waves x 32)

typedef __attribute__((ext_vector_type(8))) short bf16x8;
typedef __attribute__((ext_vector_type(4))) float f32x4;

__device__ __forceinline__ unsigned short f32_bf16_rn(float x) {
    unsigned u = __builtin_bit_cast(unsigned, x);
    unsigned r = (u + 0x7FFFu + ((u >> 16) & 1u)) >> 16;   // round-to-nearest-even
    return (unsigned short)r;
}
__device__ __forceinline__ float bf16_f32(unsigned short h) {
    unsigned u = ((unsigned)h) << 16;
    return __builtin_bit_cast(float, u);
}

// prep: ee[k]=|e_k|^2 (bit-exact sequential f32, = reference), interleaved
// two-term bf16 codebook ehl[k*128 + d]=hi, [.. +64+d]=lo, and transposed
// f32 codebook embT[d*512 + k] (for the coalesced exact slow path).
__global__ void prep(const float* __restrict__ emb, float* __restrict__ ee,
                     unsigned short* __restrict__ ehl, float* __restrict__ embT) {
#pragma clang fp contract(off)
    int k = blockIdx.x * 256 + threadIdx.x;
    if (k >= K_CODES) return;
    const float* w = emb + k * D_DIM;
    float acc = 0.f;
    for (int d = 0; d < D_DIM; ++d) {
        float v = w[d];
        float q = v * v; acc = acc + q;
        unsigned short h = f32_bf16_rn(v);
        ehl[k * 128 + d]      = h;
        ehl[k * 128 + 64 + d] = f32_bf16_rn(v - bf16_f32(h));
        embT[d * K_CODES + k] = v;
    }
    ee[k] = acc;
}

// ROUND-14 STRUCTURE (passed both validations, 66.3 us) with two scheduling
// changes, no algorithm change:
//  1. z global loads issued BEFORE the staging barrier (f32 into rz[]),
//     converted to bf16 fragments after -- z HBM latency hides under staging.
//  2. gct loop unroll 2 -> 4 so the compiler can software-pipeline the
//     ds_read_b128 fragment loads across iterations (VGPR cap 128 at (1024,4);
//     round 14's VGPR=64 showed zero prefetch depth).
// Numerics byte-identical (absmax 0.0 rounds 10-12, 14): single-pass per-row
// top-2 via 16x16x32 bf16 MFMA, two-term z/e split, MU-gap certificate,
// bit-exact coalesced slow path (sequential zz, d-ascending fma, first-
// occurrence argmin).
__global__ __launch_bounds__(TPB, 4) void vq_persist(const float* __restrict__ zin,
                                                     const float* __restrict__ emb,
                                                     const float* __restrict__ ee,
                                                     const unsigned short* __restrict__ ehl,
                                                     const float* __restrict__ embT,
                                                     float* __restrict__ out) {
#pragma clang fp contract(off)
    __shared__ __attribute__((aligned(16))) short s_cb[K_CODES * 128]; // 128 KB
    __shared__ __attribute__((aligned(16))) float s_ee[K_CODES];       // 2 KB

    const int tid  = threadIdx.x;
    const int wid  = tid >> 6;           // 0..15
    const int lane = tid & 63;
    const int l15  = lane & 15;
    const int lq   = lane >> 4;          // 0..3 = k-quarter

    const int rowbase = blockIdx.x * RPB + wid * 32;

    // ---- issue z loads FIRST (f32, 32 per thread); they complete while the
    // LDS staging below runs. Layout (validated rounds 7-14): col = l15,
    // k = s*32 + lq*8 + j.
    float rz[2][2][8];
#pragma unroll
    for (int rg = 0; rg < 2; ++rg) {
        const int n0 = rowbase + rg * 16 + l15;
        const float* zp = zin + (size_t)(n0 >> 12) * (D_DIM * HW) + (n0 & (HW - 1));
#pragma unroll
        for (int s = 0; s < 2; ++s)
#pragma unroll
            for (int j = 0; j < 8; ++j)
                rz[rg][s][j] = zp[(size_t)(s * 32 + lq * 8 + j) * HW];
    }

    // ---- stage whole codebook, swizzled: logical byte o (row=o>>8, c16=(o>>4)&15)
    // lands at (o & ~255) | ((c16 ^ (row&7)) << 4). 8 x 16B per thread.
#pragma unroll
    for (int r = 0; r < 8; ++r) {
        const int o = r * (TPB * 16) + tid * 16;
        const f32x4 v = *(const f32x4*)((const char*)ehl + o);
        const int row = o >> 8;
        const int c16 = (o >> 4) & 15;
        const int so  = (o & ~255) | ((c16 ^ (row & 7)) << 4);
        *(f32x4*)((char*)s_cb + so) = v;
    }
    if (tid < K_CODES) s_ee[tid] = ee[tid];
    __syncthreads();                     // the only barrier

    // ---- convert z to two-term bf16 fragments (VALU, post-barrier)
    bf16x8 zh[2][2], zl[2][2];
#pragma unroll
    for (int rg = 0; rg < 2; ++rg)
#pragma unroll
        for (int s = 0; s < 2; ++s)
#pragma unroll
            for (int j = 0; j < 8; ++j) {
                const float v = rz[rg][s][j];
                const unsigned short h = f32_bf16_rn(v);
                zh[rg][s][j] = (short)h;
                zl[rg][s][j] = (short)f32_bf16_rn(v - bf16_f32(h));
            }

    // per-lane swizzled fragment byte offsets: row = gct*16+l15 (256 B/row),
    // col16 = h*8 + s*4 + lq, swizzled by row&7 = l15&7
    int fb[4];
#pragma unroll
    for (int h = 0; h < 2; ++h)
#pragma unroll
        for (int s = 0; s < 2; ++s)
            fb[h * 2 + s] = l15 * 256 + (((h * 8 + s * 4 + lq) ^ (l15 & 7)) << 4);

    float m1[2] = {3.4e38f, 3.4e38f}, m2[2] = {3.4e38f, 3.4e38f};
    int   i1[2] = {0, 0};

#pragma unroll 4
    for (int gct = 0; gct < 32; ++gct) {
        const char* cb = (const char*)s_cb + gct * 4096;
        const bf16x8 ah0 = *(const bf16x8*)(cb + fb[0]);
        const bf16x8 ah1 = *(const bf16x8*)(cb + fb[1]);
        const bf16x8 al0 = *(const bf16x8*)(cb + fb[2]);
        const bf16x8 al1 = *(const bf16x8*)(cb + fb[3]);
        const f32x4 ev = *(const f32x4*)&s_ee[gct * 16 + lq * 4];
#pragma unroll
        for (int rg = 0; rg < 2; ++rg) {
            f32x4 a0 = {0.f,0.f,0.f,0.f}, a1 = {0.f,0.f,0.f,0.f}, a2 = {0.f,0.f,0.f,0.f};
            a0 = __builtin_amdgcn_mfma_f32_16x16x32_bf16(ah0, zh[rg][0], a0, 0, 0, 0);
            a1 = __builtin_amdgcn_mfma_f32_16x16x32_bf16(al0, zh[rg][0], a1, 0, 0, 0);
            a2 = __builtin_amdgcn_mfma_f32_16x16x32_bf16(ah0, zl[rg][0], a2, 0, 0, 0);
            a0 = __builtin_amdgcn_mfma_f32_16x16x32_bf16(ah1, zh[rg][1], a0, 0, 0, 0);
            a1 = __builtin_amdgcn_mfma_f32_16x16x32_bf16(al1, zh[rg][1], a1, 0, 0, 0);
            a2 = __builtin_amdgcn_mfma_f32_16x16x32_bf16(ah1, zl[rg][1], a2, 0, 0, 0);
#pragma unroll
            for (int r = 0; r < 4; ++r) {
                const float ssum = (a0[r] + a1[r]) + a2[r];
                const float dist = __builtin_fmaf(-2.f, ssum, ev[r]);
                const float hi   = fmaxf(m1[rg], dist);
                m2[rg] = fminf(m2[rg], hi);
                i1[rg] = (dist < m1[rg]) ? (gct * 16 + lq * 4 + r) : i1[rg];
                m1[rg] = fminf(m1[rg], dist);
            }
        }
    }

    // merge top-2 across the 4 k-quarters; afterwards every lane holds the
    // final (m1,i1,m2) for row rg*16 + l15
#pragma unroll
    for (int rg = 0; rg < 2; ++rg) {
#pragma unroll
        for (int mk = 16; mk <= 32; mk <<= 1) {
            const float om1 = __shfl_xor(m1[rg], mk, 64);
            const float om2 = __shfl_xor(m2[rg], mk, 64);
            const int   oi  = __shfl_xor(i1[rg], mk, 64);
            const float hi  = fmaxf(m1[rg], om1);
            m2[rg] = fminf(fminf(m2[rg], om2), hi);
            i1[rg] = (om1 < m1[rg]) ? oi : i1[rg];
            m1[rg] = fminf(m1[rg], om1);
        }
    }

    int w[2] = {i1[0], i1[1]};           // winner per (rg, l15), kept in registers

#pragma unroll
    for (int rg = 0; rg < 2; ++rg) {
        const bool flagged = (m2[rg] <= m1[rg] + MU);
        unsigned long long fmask = __ballot(flagged) & 0xFFFFull;

        // slow path: bit-exact full scan for ambiguous rows, wave-cooperative.
        // Lane L owns codes L*8+j; embT reads fully coalesced (f32x4 pairs).
        while (fmask) {
            const int R = __builtin_ctzll(fmask);
            fmask &= fmask - 1;
            const int n = rowbase + rg * 16 + R;
            const float* zq = zin + (size_t)(n >> 12) * (D_DIM * HW) + (n & (HW - 1));

            float zz = 0.f;                         // sequential, separate rounding
            for (int d = 0; d < D_DIM; ++d) {
                const float v = zq[(size_t)d * HW]; // wave-uniform addr -> s_load
                const float q = v * v; zz = zz + q;
            }
            float dot[8];
#pragma unroll
            for (int j = 0; j < 8; ++j) dot[j] = 0.f;
            for (int d = 0; d < D_DIM; ++d) {
                const float zd = zq[(size_t)d * HW];
                const float* er = embT + d * K_CODES + lane * 8;
                const f32x4 e0 = *(const f32x4*)(er);
                const f32x4 e1 = *(const f32x4*)(er + 4);
#pragma unroll
                for (int j = 0; j < 4; ++j) {
                    dot[j]     = __builtin_fmaf(e0[j], zd, dot[j]);
                    dot[j + 4] = __builtin_fmaf(e1[j], zd, dot[j + 4]);
                }
            }
            float bd = 3.4e38f; int bidx = 0;
#pragma unroll
            for (int j = 0; j < 8; ++j) {
                const float mm = 2.0f * dot[j];
                const float s  = zz - mm;
                const float dist = s + s_ee[lane * 8 + j];
                if (dist < bd) { bd = dist; bidx = lane * 8 + j; }  // strict < : lowest j
            }
#pragma unroll
            for (int mk = 1; mk <= 32; mk <<= 1) {  // lexicographic (dist, idx) min
                const float od = __shfl_xor(bd, mk, 64);
                const int   oi = __shfl_xor(bidx, mk, 64);
                const bool take = (od < bd) || (od == bd && oi < bidx);
                bd   = take ? od : bd;
                bidx = take ? oi : bidx;
            }
            if ((lane & 15) == R) w[rg] = bidx;     // bidx uniform across wave
        }
    }

    // ---- epilogue (per-wave, no sync): lane covers row = lane&31 at
    // d-half lane>>5. Winner for that row is in this lane's w[(lane>>4)&1].
    const int myrow = lane & 31;
    const int win   = w[(lane >> 4) & 1];
    const int n2    = rowbase + myrow;
    const int d0    = (lane >> 5) * 32;
    float* o1 = out + (size_t)(n2 >> 12) * (D_DIM * HW) + (n2 & (HW - 1));
    float* o2 = o1 + HALF;
    const float* wv = emb + (size_t)win * D_DIM + d0;
#pragma unroll
    for (int q = 0; q < 8; ++q) {
        const f32x4 v = *(const f32x4*)(wv + q * 4);
#pragma unroll
        for (int i = 0; i < 4; ++i) {
            const int d = d0 + q * 4 + i;
            o1[(size_t)d * HW] = v[i];
            o2[(size_t)d * HW] = v[i];
        }
    }
}

// fallback (validated round-2 kernel) if ws too small
__global__ __launch_bounds__(256) void vq_fallback(const float* __restrict__ zin,
                                                   const float* __restrict__ emb,
                                                   float* __restrict__ out) {
#pragma clang fp contract(off)
    __shared__ float s_ee[K_CODES];
    const int tid = threadIdx.x;
    for (int k = tid; k < K_CODES; k += 256) {
        const float* w = emb + k * D_DIM;
        float acc = 0.f;
        for (int d = 0; d < D_DIM; ++d) { float q = w[d] * w[d]; acc = acc + q; }
        s_ee[k] = acc;
    }
    __syncthreads();
    const int n = blockIdx.x * 256 + tid;
    const int b = n >> 12;
    const int p = n & (HW - 1);
    const float* zp = zin + (size_t)b * (D_DIM * HW) + p;
    float zr[D_DIM];
#pragma unroll
    for (int d = 0; d < D_DIM; ++d) zr[d] = zp[(size_t)d * HW];
    float zz = 0.f;
#pragma unroll
    for (int d = 0; d < D_DIM; ++d) { float q = zr[d] * zr[d]; zz = zz + q; }
    float best = 3.4e38f; int bi = 0;
    for (int k0 = 0; k0 < K_CODES; k0 += 8) {
        const float* w = emb + (size_t)k0 * D_DIM;
        float dot[8];
#pragma unroll
        for (int j = 0; j < 8; ++j) dot[j] = 0.f;
#pragma unroll
        for (int d = 0; d < D_DIM; ++d) {
            const float z = zr[d];
#pragma unroll
            for (int j = 0; j < 8; ++j)
                dot[j] = __builtin_fmaf(w[j * D_DIM + d], z, dot[j]);
        }
#pragma unroll
        for (int j = 0; j < 8; ++j) {
            const float m = 2.0f * dot[j];
            const float s = zz - m;
            const float dist = s + s_ee[k0 + j];
            if (dist < best) { best = dist; bi = k0 + j; }
        }
    }
    const float* wb = emb + (size_t)bi * D_DIM;
    float* o1 = out + (size_t)b * (D_DIM * HW) + p;
    float* o2 = o1 + HALF;
#pragma unroll
    for (int d = 0; d < D_DIM; ++d) {
        const float v = wb[d];
        o1[(size_t)d * HW] = v;
        o2[(size_t)d * HW] = v;
    }
}

extern "C" void kernel_launch(void* const* d_in, const int* in_sizes, int n_in,
                              void* d_out, int out_size, void* d_ws, size_t ws_size,
                              hipStream_t stream) {
    const float* z   = (const float*)d_in[0];
    const float* emb = (const float*)d_in[1];
    float* out = (float*)d_out;

    const size_t EHL_B  = (size_t)K_CODES * 128 * sizeof(unsigned short); // 128 KB
    const size_t EMBT_B = (size_t)K_CODES * D_DIM * sizeof(float);        // 128 KB
    const size_t need = 2048 + EHL_B + EMBT_B;                            // 258 KB
    if (ws_size >= need) {
        float* ee = (float*)d_ws;
        unsigned short* ehl = (unsigned short*)((char*)d_ws + 2048);
        float* embT = (float*)((char*)d_ws + 2048 + EHL_B);
        hipLaunchKernelGGL(prep, dim3(2), dim3(256), 0, stream, emb, ee, ehl, embT);
        hipLaunchKernelGGL(vq_persist, dim3(N_ROWS / RPB), dim3(TPB), 0, stream,
                           z, emb, ee, ehl, embT, out);
    } else {
        hipLaunchKernelGGL(vq_fallback, dim3(N_ROWS / 256), dim3(256), 0, stream,
                           z, emb, out);
    }
}